// Round 8
// baseline (467.197 us; speedup 1.0000x reference)
//
#include <hip/hip_runtime.h>
#include <hip/hip_bf16.h>

typedef __bf16 bf16x8 __attribute__((ext_vector_type(8)));
typedef __bf16 bf16x4 __attribute__((ext_vector_type(4)));
typedef float floatx4 __attribute__((ext_vector_type(4)));

#define B_    4096
#define IN_   2048
#define HID_  4096
#define NC_   1000
#define NCP_  1024

#define GLDS(g, l) __builtin_amdgcn_global_load_lds(                         \
    (__attribute__((address_space(1))) void*)(g),                            \
    (__attribute__((address_space(3))) void*)(l), 16, 0, 0)

// ---------------------------------------------------------------------------
// Transpose+convert device body: src [R][C] f32 -> dst [c][r] bf16, c range
// [64*by, 64*by+63] (c >= C zero-filled; dst padded). Stride-65 f32 tile:
// phase-1 writes conflict-free, phase-2 reads 2-way (free). 16B stores.
// ---------------------------------------------------------------------------
__device__ __forceinline__ void transpose_cvt_dev(const float* __restrict__ src,
                                                  __bf16* __restrict__ dst,
                                                  int R, int C, int bx, int by,
                                                  float* tile /* >= 64*65 f32 */) {
    const int r0 = bx * 64;
    const int c0 = by * 64;
    const int t  = threadIdx.x;
#pragma unroll
    for (int it = 0; it < 4; ++it) {
        int lin = it * 256 + t;
        int sr = lin >> 4, c4 = lin & 15;
        int cb = c0 + c4 * 4;
        const float* s = src + (size_t)(r0 + sr) * C;
        float4 v;
        if (cb + 3 < C) {
            v = *(const float4*)(s + cb);
        } else {
            v.x = (cb + 0 < C) ? s[cb + 0] : 0.f;
            v.y = (cb + 1 < C) ? s[cb + 1] : 0.f;
            v.z = (cb + 2 < C) ? s[cb + 2] : 0.f;
            v.w = (cb + 3 < C) ? s[cb + 3] : 0.f;
        }
        tile[(c4 * 4 + 0) * 65 + sr] = v.x;
        tile[(c4 * 4 + 1) * 65 + sr] = v.y;
        tile[(c4 * 4 + 2) * 65 + sr] = v.z;
        tile[(c4 * 4 + 3) * 65 + sr] = v.w;
    }
    __syncthreads();
#pragma unroll
    for (int it = 0; it < 2; ++it) {
        int lin = it * 256 + t;                 // 0..511
        int dr = lin >> 3, q8 = lin & 7;
        bf16x8 o;
#pragma unroll
        for (int j = 0; j < 8; ++j) o[j] = (__bf16)tile[dr * 65 + q8 * 8 + j];
        *(bf16x8*)(dst + (size_t)(c0 + dr) * R + r0 + q8 * 8) = o;
    }
}

// ---------------------------------------------------------------------------
// GEMM core v2: BK=32, double-buffered LDS (2 x 8 KB per matrix = 32 KB
// total, same occupancy as R2's single-buffer BK=64). Stage tile k+1 into
// buf p^1 BEFORE computing tile k from buf p -> the compiler's
// vmcnt(0)-before-barrier drain overlaps the compute phase instead of
// stalling cold (R2..R7: that drain was ~700 cyc of the 1200 cyc/iter).
// One barrier/iter x 128 iters == same barrier count as before.
// Swizzle (64 B rows = 4 chunks): slot (r,c) holds global chunk
// c ^ ((r>>1)&3); frag read chunk lr ^ ((row>>1)&3) -> phase
// (4*lc + lr^((lc>>1)&3))&7 covers all 8 bank-groups, 2 lanes each (free)
// -- same phase statistics as the R2-measured-zero pattern.
// Correctness of single barrier: barrier at end of iter k-1 ensures all
// waves finished READING buf[(k+1)%2] before iter k's DMA overwrites it.
// ---------------------------------------------------------------------------
template <bool RELU, bool OUT_BF16>
__device__ __forceinline__ void gemm_core(const __bf16* __restrict__ A,
                                          const __bf16* __restrict__ Bt,
                                          const float* __restrict__ bias,
                                          void* __restrict__ Cv,
                                          int M, int K, int Nstore,
                                          int bx, int by, int kBeg, int kEnd,
                                          __bf16* sA, __bf16* sB) {
    const int tid   = threadIdx.x;
    const int lane  = tid & 63;
    const int wave  = tid >> 6;
    const int wr    = wave >> 1;
    const int wc    = wave & 1;
    const int mBase = by * 128;
    const int nBase = bx * 128;
    const int lr    = lane >> 4;
    const int lc    = lane & 15;

    // Per-thread staging slots (fixed across iters): lin = it*256+tid,
    // r = lin>>2, c = lin&3, global chunk kc = c ^ ((r>>1)&3).
    const int lin0 = tid, lin1 = 256 + tid;
    const int r0s = lin0 >> 2, c0s = (lin0 & 3) ^ ((r0s >> 1) & 3);
    const int r1s = lin1 >> 2, c1s = (lin1 & 3) ^ ((r1s >> 1) & 3);
    const __bf16* gA0 = A  + (size_t)(mBase + r0s) * K + kBeg + c0s * 8;
    const __bf16* gA1 = A  + (size_t)(mBase + r1s) * K + kBeg + c1s * 8;
    const __bf16* gB0 = Bt + (size_t)(nBase + r0s) * K + kBeg + c0s * 8;
    const __bf16* gB1 = Bt + (size_t)(nBase + r1s) * K + kBeg + c1s * 8;

    // Frag-read LDS offsets (bf16 units), fixed across iters.
    int offA[4], offB[4];
#pragma unroll
    for (int i = 0; i < 4; ++i) {
        int rowA = wr * 64 + i * 16 + lc;
        offA[i] = rowA * 32 + (lr ^ ((rowA >> 1) & 3)) * 8;
        int rowB = wc * 64 + i * 16 + lc;
        offB[i] = rowB * 32 + (lr ^ ((rowB >> 1) & 3)) * 8;
    }

    floatx4 acc[4][4];
#pragma unroll
    for (int i = 0; i < 4; ++i)
#pragma unroll
        for (int j = 0; j < 4; ++j) acc[i][j] = (floatx4)0.f;

    // Stage tile 0 into buffer 0.
    GLDS(gA0, sA + lin0 * 8);
    GLDS(gA1, sA + lin1 * 8);
    GLDS(gB0, sB + lin0 * 8);
    GLDS(gB1, sB + lin1 * 8);
    gA0 += 32; gA1 += 32; gB0 += 32; gB1 += 32;
    __builtin_amdgcn_s_waitcnt(0);
    __syncthreads();

    const int nIter = (kEnd - kBeg) >> 5;
    int p = 0;
    for (int itk = 0; itk < nIter; ++itk) {
        // Prefetch next tile into the other buffer (DMA, async).
        if (itk + 1 < nIter) {
            const int q = (p ^ 1) * 4096;
            GLDS(gA0, sA + q + lin0 * 8);
            GLDS(gA1, sA + q + lin1 * 8);
            GLDS(gB0, sB + q + lin0 * 8);
            GLDS(gB1, sB + q + lin1 * 8);
            gA0 += 32; gA1 += 32; gB0 += 32; gB1 += 32;
        }
        // Compute on buffer p while the prefetch flies.
        const int pb = p * 4096;
        bf16x8 af[4], bfr[4];
#pragma unroll
        for (int i = 0; i < 4; ++i) af[i]  = *(const bf16x8*)(sA + pb + offA[i]);
#pragma unroll
        for (int j = 0; j < 4; ++j) bfr[j] = *(const bf16x8*)(sB + pb + offB[j]);
#pragma unroll
        for (int i = 0; i < 4; ++i)
#pragma unroll
            for (int j = 0; j < 4; ++j)
                acc[i][j] = __builtin_amdgcn_mfma_f32_16x16x32_bf16(af[i], bfr[j], acc[i][j], 0, 0, 0);
        __syncthreads();   // vmcnt(0) drain here overlaps the compute above
        p ^= 1;
    }

#pragma unroll
    for (int j = 0; j < 4; ++j) {
        int col = nBase + wc * 64 + j * 16 + lc;
        if (col < Nstore) {
            float bv = bias ? bias[col] : 0.f;
#pragma unroll
            for (int i = 0; i < 4; ++i) {
                int rowb = mBase + wr * 64 + i * 16 + lr * 4;
#pragma unroll
                for (int r = 0; r < 4; ++r) {
                    float v = acc[i][j][r] + bv;
                    if (RELU) v = fmaxf(v, 0.f);
                    if (OUT_BF16)
                        ((__bf16*)Cv)[(size_t)(rowb + r) * Nstore + col] = (__bf16)v;
                    else
                        ((float*)Cv)[(size_t)(rowb + r) * Nstore + col] = v;
                }
            }
        }
    }
}

// ---------------------------------------------------------------------------
// prep1: blocks [0,4096) x f32->bf16 (2048 elem/block); [4096,6144) w1
// transpose ([2048][4096] -> w1t [4096][2048]). Whole-block branch.
// ---------------------------------------------------------------------------
__global__ __launch_bounds__(256) void prep1(const float* __restrict__ x,
                                             __bf16* __restrict__ xb,
                                             const float* __restrict__ w1,
                                             __bf16* __restrict__ w1t) {
    __shared__ float tile[64 * 65];
    const int b = blockIdx.x;
    if (b < 4096) {
        int i = (b * 256 + (int)threadIdx.x) * 8;
        float4 a = *(const float4*)(x + i);
        float4 c = *(const float4*)(x + i + 4);
        bf16x8 o;
        o[0] = (__bf16)a.x; o[1] = (__bf16)a.y; o[2] = (__bf16)a.z; o[3] = (__bf16)a.w;
        o[4] = (__bf16)c.x; o[5] = (__bf16)c.y; o[6] = (__bf16)c.z; o[7] = (__bf16)c.w;
        *(bf16x8*)(xb + i) = o;
    } else {
        int l = b - 4096;                       // 32 r-tiles x 64 c-tiles
        transpose_cvt_dev(w1, w1t, IN_, HID_, l & 31, l >> 5, tile);
    }
}

// ---------------------------------------------------------------------------
// gemm1_fused: blocks [0,1024) = layer-1 GEMM (fills all CUs immediately);
// [1024,5120) = w2 transpose; [5120,6144) = w3 transpose (+zero-fill rows
// 1000..1023). Transposes (pure-memory) overlap the MFMA-bound GEMM.
// ---------------------------------------------------------------------------
__global__ __launch_bounds__(256, 2) void gemm1_fused(const __bf16* __restrict__ xb,
                                                      const __bf16* __restrict__ w1t,
                                                      const float* __restrict__ b1,
                                                      __bf16* __restrict__ h1,
                                                      const float* __restrict__ w2,
                                                      __bf16* __restrict__ w2t,
                                                      const float* __restrict__ w3,
                                                      __bf16* __restrict__ w3t) {
    __shared__ float smem[8192];                // 32 KB, shared by both roles
    const int b = blockIdx.x;
    if (b < 1024) {
        __bf16* sA = (__bf16*)smem;             // 2 x 4096 bf16 (dbuf)
        __bf16* sB = sA + 8192;
        gemm_core<true, true>(xb, w1t, b1, h1, B_, IN_, HID_,
                              b & 31, b >> 5, 0, IN_, sA, sB);
    } else if (b < 5120) {
        int l = b - 1024;                       // 64 x 64 tiles
        transpose_cvt_dev(w2, w2t, HID_, HID_, l & 63, l >> 6, smem);
    } else {
        int l = b - 5120;                       // 64 x 16 tiles
        transpose_cvt_dev(w3, w3t, HID_, NC_, l & 63, l >> 6, smem);
    }
}

// ---------------------------------------------------------------------------
// Layer-2 GEMM dispatch (dbuf core).
// ---------------------------------------------------------------------------
template <bool RELU, bool OUT_BF16>
__global__ __launch_bounds__(256, 2) void gemm_bt(const __bf16* __restrict__ A,
                                                  const __bf16* __restrict__ Bt,
                                                  const float* __restrict__ bias,
                                                  void* __restrict__ Cv,
                                                  int M, int K, int Nstore) {
    __shared__ __bf16 sA[2 * 128 * 32];
    __shared__ __bf16 sB[2 * 128 * 32];
    gemm_core<RELU, OUT_BF16>(A, Bt, bias, Cv, M, K, Nstore,
                              blockIdx.x, blockIdx.y, 0, K, sA, sB);
}

// ---------------------------------------------------------------------------
// Layer-3 split-K x2 (512 blocks = 2/CU): P[z][M][1024] = partial GEMM.
// ---------------------------------------------------------------------------
__global__ __launch_bounds__(256, 2) void gemm_sk(const __bf16* __restrict__ A,
                                                  const __bf16* __restrict__ Bt,
                                                  float* __restrict__ P,
                                                  int M, int KH, int Ktot) {
    __shared__ __bf16 sA[2 * 128 * 32];
    __shared__ __bf16 sB[2 * 128 * 32];
    const int z = blockIdx.z;
    float* Pz = P + (size_t)z * M * NCP_;
    gemm_core<false, false>(A, Bt, (const float*)nullptr, Pz, M, Ktot, NCP_,
                            blockIdx.x, blockIdx.y, z * KH, (z + 1) * KH, sA, sB);
}

// ---------------------------------------------------------------------------
// out[m][c] = P0[m][c] + P1[m][c] + b3[c], c < 1000. grid (4, 4096).
// ---------------------------------------------------------------------------
__global__ __launch_bounds__(256) void reduce_bias(const float* __restrict__ P,
                                                   const float* __restrict__ b3,
                                                   float* __restrict__ out) {
    int c = blockIdx.x * 256 + threadIdx.x;
    int m = blockIdx.y;
    if (c < NC_)
        out[(size_t)m * NC_ + c] =
            P[(size_t)m * NCP_ + c] + P[(size_t)(B_ + m) * NCP_ + c] + b3[c];
}

extern "C" void kernel_launch(void* const* d_in, const int* in_sizes, int n_in,
                              void* d_out, int out_size, void* d_ws, size_t ws_size,
                              hipStream_t stream) {
    const float* x  = (const float*)d_in[0];
    const float* w1 = (const float*)d_in[1];
    const float* b1 = (const float*)d_in[2];
    const float* w2 = (const float*)d_in[3];
    const float* b2 = (const float*)d_in[4];
    const float* w3 = (const float*)d_in[5];
    const float* b3 = (const float*)d_in[6];
    float* out = (float*)d_out;

    // ws (MiB): [0,16) xb | [16,32) w1t | [32,64) w2t | [64,72) w3t |
    // [72,104) h1. h2 aliases [0,32) (xb/w1t dead after gemm1);
    // split-K partials P alias [72,104) (h1 dead after gemm2). 104 MiB.
    char* ws = (char*)d_ws;
    __bf16* xb  = (__bf16*)(ws);
    __bf16* w1t = (__bf16*)(ws + (16u << 20));
    __bf16* w2t = (__bf16*)(ws + (32u << 20));
    __bf16* w3t = (__bf16*)(ws + (64u << 20));
    __bf16* h1  = (__bf16*)(ws + (72u << 20));
    __bf16* h2  = (__bf16*)(ws);
    float*  P   = (float*)(ws + (72u << 20));

    prep1<<<6144, 256, 0, stream>>>(x, xb, w1, w1t);

    gemm1_fused<<<6144, 256, 0, stream>>>(xb, w1t, b1, h1, w2, w2t, w3, w3t);

    gemm_bt<true, true><<<dim3(HID_ / 128, B_ / 128), 256, 0, stream>>>(
        h1, w2t, b2, h2, B_, HID_, HID_);

    gemm_sk<<<dim3(NCP_ / 128, B_ / 128, 2), 256, 0, stream>>>(
        h2, w3t, P, B_, HID_ / 2, HID_);
    reduce_bias<<<dim3(NCP_ / 256, B_), 256, 0, stream>>>(P, b3, out);
}

// Round 9
// 421.468 us; speedup vs baseline: 1.1085x; 1.1085x over previous
//
#include <hip/hip_runtime.h>
#include <hip/hip_bf16.h>

typedef __bf16 bf16x8 __attribute__((ext_vector_type(8)));
typedef __bf16 bf16x4 __attribute__((ext_vector_type(4)));
typedef float floatx4 __attribute__((ext_vector_type(4)));

#define B_    4096
#define IN_   2048
#define HID_  4096
#define NC_   1000
#define NCP_  1024

// ---------------------------------------------------------------------------
// Transpose+convert device body: src [R][C] f32 -> dst [c][r] bf16, c range
// [64*by, 64*by+63] (c >= C zero-filled; dst padded). Stride-65 f32 tile:
// phase-1 writes conflict-free, phase-2 reads 2-way (free). 16B stores.
// ---------------------------------------------------------------------------
__device__ __forceinline__ void transpose_cvt_dev(const float* __restrict__ src,
                                                  __bf16* __restrict__ dst,
                                                  int R, int C, int bx, int by,
                                                  float* tile /* >= 64*65 f32 */) {
    const int r0 = bx * 64;
    const int c0 = by * 64;
    const int t  = threadIdx.x;
#pragma unroll
    for (int it = 0; it < 4; ++it) {
        int lin = it * 256 + t;
        int sr = lin >> 4, c4 = lin & 15;
        int cb = c0 + c4 * 4;
        const float* s = src + (size_t)(r0 + sr) * C;
        float4 v;
        if (cb + 3 < C) {
            v = *(const float4*)(s + cb);
        } else {
            v.x = (cb + 0 < C) ? s[cb + 0] : 0.f;
            v.y = (cb + 1 < C) ? s[cb + 1] : 0.f;
            v.z = (cb + 2 < C) ? s[cb + 2] : 0.f;
            v.w = (cb + 3 < C) ? s[cb + 3] : 0.f;
        }
        tile[(c4 * 4 + 0) * 65 + sr] = v.x;
        tile[(c4 * 4 + 1) * 65 + sr] = v.y;
        tile[(c4 * 4 + 2) * 65 + sr] = v.z;
        tile[(c4 * 4 + 3) * 65 + sr] = v.w;
    }
    __syncthreads();
#pragma unroll
    for (int it = 0; it < 2; ++it) {
        int lin = it * 256 + t;                 // 0..511
        int dr = lin >> 3, q8 = lin & 7;
        bf16x8 o;
#pragma unroll
        for (int j = 0; j < 8; ++j) o[j] = (__bf16)tile[dr * 65 + q8 * 8 + j];
        *(bf16x8*)(dst + (size_t)(c0 + dr) * R + r0 + q8 * 8) = o;
    }
}

// ---------------------------------------------------------------------------
// XCD-aware swizzle for a 32x32 tile grid: linear bid -> (bx, by) such that
// blocks with equal bid%8 (typical XCD assignment) form a compact 16m x 8n
// patch -> per-XCD per-k-step working set 24 tiles (384 KB) instead of
// 36 tiles dominated by all-32 A-tiles. Heuristic only (mapping undefined);
// wrong mapping degrades to a harmless permutation.
// ---------------------------------------------------------------------------
__device__ __forceinline__ void swizzle32x32(int bid, int& bx, int& by) {
    int xcd = bid & 7;
    int q   = bid >> 3;                         // 0..127
    by = ((xcd >> 2) << 4) + (q & 15);          // patch row: 2 x 16
    bx = ((xcd & 3) << 3) + (q >> 4);           // patch col: 4 x 8
}

// ---------------------------------------------------------------------------
// GEMM core (R2-verified, DO NOT PERTURB): 128x128 block, 4 waves (2x2),
// wave 64x64 as 4x4 MFMA 16x16x32 frags. XOR swizzle: LDS slot (r,c) holds
// global chunk c^(r&7); frag reads use chunk (kk*4+lr)^(lc&7) ->
// SQ_LDS_BANK_CONFLICT == 0 (measured R2/R4/R5/R6/R7, 1074 TF).
// Measured regressions -- do not re-try:
//   R3: 32x32x16 frag pattern (rows keyed by lane&31) -> 1.7e7 conflicts.
//   R6: 128x64 tile -> MFMA-per-barrier density loss > residency gain.
//   R8: BK=32 double-buffer -> compute phase (155 cyc) << staging latency
//       (900 cyc); halved MFMA-per-drain, gemm2 128->164 us.
// ---------------------------------------------------------------------------
template <bool RELU, bool OUT_BF16>
__device__ __forceinline__ void gemm_core(const __bf16* __restrict__ A,
                                          const __bf16* __restrict__ Bt,
                                          const float* __restrict__ bias,
                                          void* __restrict__ Cv,
                                          int M, int K, int Nstore,
                                          int bx, int by,
                                          __bf16* sA, __bf16* sB) {
    const int tid   = threadIdx.x;
    const int lane  = tid & 63;
    const int wave  = tid >> 6;
    const int wr    = wave >> 1;
    const int wc    = wave & 1;
    const int mBase = by * 128;
    const int nBase = bx * 128;
    const int lr    = lane >> 4;
    const int lc    = lane & 15;

    floatx4 acc[4][4];
#pragma unroll
    for (int i = 0; i < 4; ++i)
#pragma unroll
        for (int j = 0; j < 4; ++j) acc[i][j] = (floatx4)0.f;

    for (int k0 = 0; k0 < K; k0 += 64) {
#pragma unroll
        for (int it = 0; it < 4; ++it) {
            int lin = it * 256 + tid;
            int r   = lin >> 3;
            int kc  = (lin & 7) ^ (r & 7);          // XOR swizzle
            const __bf16* ga = A  + (size_t)(mBase + r) * K + k0 + kc * 8;
            const __bf16* gb = Bt + (size_t)(nBase + r) * K + k0 + kc * 8;
            __builtin_amdgcn_global_load_lds(
                (__attribute__((address_space(1))) void*)ga,
                (__attribute__((address_space(3))) void*)(sA + lin * 8), 16, 0, 0);
            __builtin_amdgcn_global_load_lds(
                (__attribute__((address_space(1))) void*)gb,
                (__attribute__((address_space(3))) void*)(sB + lin * 8), 16, 0, 0);
        }
        __builtin_amdgcn_s_waitcnt(0);
        __syncthreads();

#pragma unroll
        for (int kk = 0; kk < 2; ++kk) {
            const int sw = (kk * 4 + lr) ^ (lc & 7);   // swizzled chunk
            bf16x8 af[4], bfr[4];
#pragma unroll
            for (int i = 0; i < 4; ++i)
                af[i] = *(const bf16x8*)(sA + (wr * 64 + i * 16 + lc) * 64 + sw * 8);
#pragma unroll
            for (int j = 0; j < 4; ++j)
                bfr[j] = *(const bf16x8*)(sB + (wc * 64 + j * 16 + lc) * 64 + sw * 8);
#pragma unroll
            for (int i = 0; i < 4; ++i)
#pragma unroll
                for (int j = 0; j < 4; ++j)
                    acc[i][j] = __builtin_amdgcn_mfma_f32_16x16x32_bf16(af[i], bfr[j], acc[i][j], 0, 0, 0);
        }
        __syncthreads();
    }

#pragma unroll
    for (int j = 0; j < 4; ++j) {
        int col = nBase + wc * 64 + j * 16 + lc;
        if (col < Nstore) {
            float bv = bias[col];
#pragma unroll
            for (int i = 0; i < 4; ++i) {
                int rowb = mBase + wr * 64 + i * 16 + lr * 4;
#pragma unroll
                for (int r = 0; r < 4; ++r) {
                    float v = acc[i][j][r] + bv;
                    if (RELU) v = fmaxf(v, 0.f);
                    if (OUT_BF16)
                        ((__bf16*)Cv)[(size_t)(rowb + r) * Nstore + col] = (__bf16)v;
                    else
                        ((float*)Cv)[(size_t)(rowb + r) * Nstore + col] = v;
                }
            }
        }
    }
}

// ---------------------------------------------------------------------------
// prep1: blocks [0,4096) x f32->bf16 (2048 elem/block); [4096,6144) w1
// transpose ([2048][4096] -> w1t [4096][2048]). Whole-block branch.
// ---------------------------------------------------------------------------
__global__ __launch_bounds__(256) void prep1(const float* __restrict__ x,
                                             __bf16* __restrict__ xb,
                                             const float* __restrict__ w1,
                                             __bf16* __restrict__ w1t) {
    __shared__ float tile[64 * 65];
    const int b = blockIdx.x;
    if (b < 4096) {
        int i = (b * 256 + (int)threadIdx.x) * 8;
        float4 a = *(const float4*)(x + i);
        float4 c = *(const float4*)(x + i + 4);
        bf16x8 o;
        o[0] = (__bf16)a.x; o[1] = (__bf16)a.y; o[2] = (__bf16)a.z; o[3] = (__bf16)a.w;
        o[4] = (__bf16)c.x; o[5] = (__bf16)c.y; o[6] = (__bf16)c.z; o[7] = (__bf16)c.w;
        *(bf16x8*)(xb + i) = o;
    } else {
        int l = b - 4096;                       // 32 r-tiles x 64 c-tiles
        transpose_cvt_dev(w1, w1t, IN_, HID_, l & 31, l >> 5, tile);
    }
}

// ---------------------------------------------------------------------------
// gemm1_fused: blocks [0,1024) = layer-1 GEMM (XCD-swizzled tile mapping,
// fills all CUs immediately); [1024,5120) = w2 transpose; [5120,6144) = w3
// transpose (+zero-fill rows 1000..1023). Transposes (pure-memory) overlap
// the MFMA-bound GEMM; outputs consumed only by later dispatches.
// ---------------------------------------------------------------------------
__global__ __launch_bounds__(256, 2) void gemm1_fused(const __bf16* __restrict__ xb,
                                                      const __bf16* __restrict__ w1t,
                                                      const float* __restrict__ b1,
                                                      __bf16* __restrict__ h1,
                                                      const float* __restrict__ w2,
                                                      __bf16* __restrict__ w2t,
                                                      const float* __restrict__ w3,
                                                      __bf16* __restrict__ w3t) {
    __shared__ float smem[8192];                // 32 KB, shared by both roles
    const int b = blockIdx.x;
    if (b < 1024) {
        __bf16* sA = (__bf16*)smem;
        __bf16* sB = sA + 128 * 64;
        int bx, by;
        swizzle32x32(b, bx, by);
        gemm_core<true, true>(xb, w1t, b1, h1, B_, IN_, HID_, bx, by, sA, sB);
    } else if (b < 5120) {
        int l = b - 1024;                       // 64 x 64 tiles
        transpose_cvt_dev(w2, w2t, HID_, HID_, l & 63, l >> 6, smem);
    } else {
        int l = b - 5120;                       // 64 x 16 tiles
        transpose_cvt_dev(w3, w3t, HID_, NC_, l & 63, l >> 6, smem);
    }
}

// ---------------------------------------------------------------------------
// Layer-2 GEMM dispatch (128x128 core, XCD-swizzled 32x32 tile mapping).
// ---------------------------------------------------------------------------
template <bool RELU, bool OUT_BF16>
__global__ __launch_bounds__(256, 2) void gemm_bt(const __bf16* __restrict__ A,
                                                  const __bf16* __restrict__ Bt,
                                                  const float* __restrict__ bias,
                                                  void* __restrict__ Cv,
                                                  int M, int K, int Nstore) {
    __shared__ __bf16 sA[128 * 64];
    __shared__ __bf16 sB[128 * 64];
    int bx = blockIdx.x, by = blockIdx.y;
    if (gridDim.x == 32 && gridDim.y == 32) {
        int bid = by * 32 + bx;
        swizzle32x32(bid, bx, by);
    }
    gemm_core<RELU, OUT_BF16>(A, Bt, bias, Cv, M, K, Nstore, bx, by, sA, sB);
}

// ---------------------------------------------------------------------------
// Layer-3 split-K x2 (512 blocks = 2/CU): P[z][M][1024] = partial GEMM.
// ---------------------------------------------------------------------------
__global__ __launch_bounds__(256, 2) void gemm_sk(const __bf16* __restrict__ A,
                                                  const __bf16* __restrict__ Bt,
                                                  float* __restrict__ P,
                                                  int M, int KH, int Ktot) {
    __shared__ __bf16 sA[128 * 64];
    __shared__ __bf16 sB[128 * 64];

    const int tid   = threadIdx.x;
    const int lane  = tid & 63;
    const int wave  = tid >> 6;
    const int wr    = wave >> 1;
    const int wc    = wave & 1;
    const int mBase = blockIdx.y * 128;
    const int nBase = blockIdx.x * 128;
    const int z     = blockIdx.z;
    const int kOff  = z * KH;
    const int lr    = lane >> 4;
    const int lc    = lane & 15;

    floatx4 acc[4][4];
#pragma unroll
    for (int i = 0; i < 4; ++i)
#pragma unroll
        for (int j = 0; j < 4; ++j) acc[i][j] = (floatx4)0.f;

    for (int k0 = kOff; k0 < kOff + KH; k0 += 64) {
#pragma unroll
        for (int it = 0; it < 4; ++it) {
            int lin = it * 256 + tid;
            int r   = lin >> 3;
            int kc  = (lin & 7) ^ (r & 7);
            const __bf16* ga = A  + (size_t)(mBase + r) * Ktot + k0 + kc * 8;
            const __bf16* gb = Bt + (size_t)(nBase + r) * Ktot + k0 + kc * 8;
            __builtin_amdgcn_global_load_lds(
                (__attribute__((address_space(1))) void*)ga,
                (__attribute__((address_space(3))) void*)(sA + lin * 8), 16, 0, 0);
            __builtin_amdgcn_global_load_lds(
                (__attribute__((address_space(1))) void*)gb,
                (__attribute__((address_space(3))) void*)(sB + lin * 8), 16, 0, 0);
        }
        __builtin_amdgcn_s_waitcnt(0);
        __syncthreads();

#pragma unroll
        for (int kk = 0; kk < 2; ++kk) {
            const int sw = (kk * 4 + lr) ^ (lc & 7);
            bf16x8 af[4], bfr[4];
#pragma unroll
            for (int i = 0; i < 4; ++i)
                af[i] = *(const bf16x8*)(sA + (wr * 64 + i * 16 + lc) * 64 + sw * 8);
#pragma unroll
            for (int j = 0; j < 4; ++j)
                bfr[j] = *(const bf16x8*)(sB + (wc * 64 + j * 16 + lc) * 64 + sw * 8);
#pragma unroll
            for (int i = 0; i < 4; ++i)
#pragma unroll
                for (int j = 0; j < 4; ++j)
                    acc[i][j] = __builtin_amdgcn_mfma_f32_16x16x32_bf16(af[i], bfr[j], acc[i][j], 0, 0, 0);
        }
        __syncthreads();
    }

    float* Pz = P + (size_t)z * M * NCP_;
#pragma unroll
    for (int j = 0; j < 4; ++j) {
        int col = nBase + wc * 64 + j * 16 + lc;
#pragma unroll
        for (int i = 0; i < 4; ++i) {
            int rowb = mBase + wr * 64 + i * 16 + lr * 4;
#pragma unroll
            for (int r = 0; r < 4; ++r)
                Pz[(size_t)(rowb + r) * NCP_ + col] = acc[i][j][r];
        }
    }
}

// ---------------------------------------------------------------------------
// out[m][c] = P0[m][c] + P1[m][c] + b3[c], c < 1000. grid (4, 4096).
// ---------------------------------------------------------------------------
__global__ __launch_bounds__(256) void reduce_bias(const float* __restrict__ P,
                                                   const float* __restrict__ b3,
                                                   float* __restrict__ out) {
    int c = blockIdx.x * 256 + threadIdx.x;
    int m = blockIdx.y;
    if (c < NC_)
        out[(size_t)m * NC_ + c] =
            P[(size_t)m * NCP_ + c] + P[(size_t)(B_ + m) * NCP_ + c] + b3[c];
}

extern "C" void kernel_launch(void* const* d_in, const int* in_sizes, int n_in,
                              void* d_out, int out_size, void* d_ws, size_t ws_size,
                              hipStream_t stream) {
    const float* x  = (const float*)d_in[0];
    const float* w1 = (const float*)d_in[1];
    const float* b1 = (const float*)d_in[2];
    const float* w2 = (const float*)d_in[3];
    const float* b2 = (const float*)d_in[4];
    const float* w3 = (const float*)d_in[5];
    const float* b3 = (const float*)d_in[6];
    float* out = (float*)d_out;

    // ws (MiB): [0,16) xb | [16,32) w1t | [32,64) w2t | [64,72) w3t |
    // [72,104) h1. h2 aliases [0,32) (xb/w1t dead after gemm1);
    // split-K partials P alias [72,104) (h1 dead after gemm2). 104 MiB.
    char* ws = (char*)d_ws;
    __bf16* xb  = (__bf16*)(ws);
    __bf16* w1t = (__bf16*)(ws + (16u << 20));
    __bf16* w2t = (__bf16*)(ws + (32u << 20));
    __bf16* w3t = (__bf16*)(ws + (64u << 20));
    __bf16* h1  = (__bf16*)(ws + (72u << 20));
    __bf16* h2  = (__bf16*)(ws);
    float*  P   = (float*)(ws + (72u << 20));

    prep1<<<6144, 256, 0, stream>>>(x, xb, w1, w1t);

    gemm1_fused<<<6144, 256, 0, stream>>>(xb, w1t, b1, h1, w2, w2t, w3, w3t);

    gemm_bt<true, true><<<dim3(HID_ / 128, B_ / 128), 256, 0, stream>>>(
        h1, w2t, b2, h2, B_, HID_, HID_);

    gemm_sk<<<dim3(NCP_ / 128, B_ / 128, 2), 256, 0, stream>>>(
        h2, w3t, P, B_, HID_ / 2, HID_);
    reduce_bias<<<dim3(NCP_ / 256, B_), 256, 0, stream>>>(P, b3, out);
}